// Round 2
// baseline (2983.377 us; speedup 1.0000x reference)
//
#include <hip/hip_runtime.h>
#include <hip/hip_bf16.h>
#include <cstdint>
#include <cstddef>

#define NUM_USER 50000
#define NUM_ITEM 50000
#define NNODES   100000
#define NEDGE    2000000
#define DIM      64

static inline size_t align_up(size_t x, size_t a) { return (x + a - 1) & ~(a - 1); }

// ---------------- graph build ----------------

__global__ void count_kernel(const int2* __restrict__ edges, int* __restrict__ cnt) {
  int e = blockIdx.x * blockDim.x + threadIdx.x;
  if (e >= NEDGE) return;
  int2 ed = edges[e];
  atomicAdd(&cnt[ed.x], 1);
  atomicAdd(&cnt[ed.y + NUM_USER], 1);
}

__global__ void dinv_kernel(const int* __restrict__ cnt, float* __restrict__ dinv) {
  int n = blockIdx.x * blockDim.x + threadIdx.x;
  if (n >= NNODES) return;
  // degree includes self-loop -> always >= 1
  dinv[n] = rsqrtf((float)(cnt[n] + 1));
}

__global__ void scan_part(const int* __restrict__ cnt, int* __restrict__ psum) {
  __shared__ int sdata[256];
  int base = blockIdx.x * 1024;
  int t = threadIdx.x;
  int s = 0;
#pragma unroll
  for (int j = 0; j < 4; ++j) {
    int i = base + t * 4 + j;
    if (i < NNODES) s += cnt[i];
  }
  sdata[t] = s;
  __syncthreads();
  for (int off = 128; off > 0; off >>= 1) {
    if (t < off) sdata[t] += sdata[t + off];
    __syncthreads();
  }
  if (t == 0) psum[blockIdx.x] = sdata[0];
}

__global__ void scan_psum_kernel(int* __restrict__ psum, int nb, int* __restrict__ indptr) {
  if (threadIdx.x == 0 && blockIdx.x == 0) {
    int run = 0;
    for (int b = 0; b < nb; ++b) { int v = psum[b]; psum[b] = run; run += v; }
    indptr[NNODES] = run;  // == 2*NEDGE
  }
}

__global__ void scan_final(const int* __restrict__ cnt, const int* __restrict__ psum,
                           int* __restrict__ indptr, int* __restrict__ cursor) {
  __shared__ int sdata[256];
  int base = blockIdx.x * 1024;
  int t = threadIdx.x;
  int v[4]; int s = 0;
#pragma unroll
  for (int j = 0; j < 4; ++j) {
    int i = base + t * 4 + j;
    v[j] = (i < NNODES) ? cnt[i] : 0;
    s += v[j];
  }
  sdata[t] = s;
  __syncthreads();
  // inclusive Hillis-Steele scan over 256 thread sums
  for (int off = 1; off < 256; off <<= 1) {
    int mine = sdata[t];
    int other = (t >= off) ? sdata[t - off] : 0;
    __syncthreads();
    sdata[t] = mine + other;
    __syncthreads();
  }
  int excl = sdata[t] - s + psum[blockIdx.x];
#pragma unroll
  for (int j = 0; j < 4; ++j) {
    int i = base + t * 4 + j;
    if (i < NNODES) { indptr[i] = excl; cursor[i] = excl; excl += v[j]; }
  }
}

__global__ void fill_kernel(const int2* __restrict__ edges, int* __restrict__ cursor,
                            int* __restrict__ col) {
  int e = blockIdx.x * blockDim.x + threadIdx.x;
  if (e >= NEDGE) return;
  int2 ed = edges[e];
  int u = ed.x, it = ed.y + NUM_USER;
  int p = atomicAdd(&cursor[u], 1);  col[p] = it;
  int q = atomicAdd(&cursor[it], 1); col[q] = u;
}

// ---------------- C[M x 64] = A[M x K] @ B[64 x K]^T (+ bias) ----------------
// f32 tiled GEMM, 64x64 output tile per block, K in chunks of 64 (K % 64 == 0).
// LDS tiles stored k-major (transposed) so the inner loop uses float4 LDS reads.

__global__ __launch_bounds__(256) void gemm_nt64(const float* __restrict__ A,
                                                 const float* __restrict__ B,
                                                 const float* __restrict__ bias,
                                                 float* __restrict__ C,
                                                 int M, int K) {
  __shared__ float At[64][68];  // At[k][r]
  __shared__ float Bt[64][68];  // Bt[k][c]
  int t  = threadIdx.x;
  int m0 = blockIdx.x * 64;
  int kg = t & 15;   // k-group: covers k = kg*4 .. kg*4+3
  int r0 = t >> 4;   // 0..15  (rows r0, r0+16, r0+32, r0+48 staged by this thread)
  int tx = t & 15;   // output col group (cols tx*4 .. +3)
  int ty = t >> 4;   // output row group (rows ty*4 .. +3)

  float acc[4][4] = {{0.f}};

  for (int k0 = 0; k0 < K; k0 += 64) {
#pragma unroll
    for (int rr = 0; rr < 4; ++rr) {
      int r = r0 + rr * 16;
      int row = m0 + r;
      float4 av;
      if (row < M) av = *(const float4*)(&A[(size_t)row * K + k0 + kg * 4]);
      else         av = make_float4(0.f, 0.f, 0.f, 0.f);
      At[kg * 4 + 0][r] = av.x; At[kg * 4 + 1][r] = av.y;
      At[kg * 4 + 2][r] = av.z; At[kg * 4 + 3][r] = av.w;
      float4 bv = *(const float4*)(&B[(size_t)r * K + k0 + kg * 4]);
      Bt[kg * 4 + 0][r] = bv.x; Bt[kg * 4 + 1][r] = bv.y;
      Bt[kg * 4 + 2][r] = bv.z; Bt[kg * 4 + 3][r] = bv.w;
    }
    __syncthreads();
#pragma unroll
    for (int kk = 0; kk < 64; ++kk) {
      float4 a = *(const float4*)(&At[kk][ty * 4]);
      float4 b = *(const float4*)(&Bt[kk][tx * 4]);
      acc[0][0] += a.x * b.x; acc[0][1] += a.x * b.y; acc[0][2] += a.x * b.z; acc[0][3] += a.x * b.w;
      acc[1][0] += a.y * b.x; acc[1][1] += a.y * b.y; acc[1][2] += a.y * b.z; acc[1][3] += a.y * b.w;
      acc[2][0] += a.z * b.x; acc[2][1] += a.z * b.y; acc[2][2] += a.z * b.z; acc[2][3] += a.z * b.w;
      acc[3][0] += a.w * b.x; acc[3][1] += a.w * b.y; acc[3][2] += a.w * b.z; acc[3][3] += a.w * b.w;
    }
    __syncthreads();
  }

  float4 bb = make_float4(0.f, 0.f, 0.f, 0.f);
  if (bias) bb = *(const float4*)(&bias[tx * 4]);
#pragma unroll
  for (int i = 0; i < 4; ++i) {
    int row = m0 + ty * 4 + i;
    if (row >= M) continue;
    float4 o;
    o.x = acc[i][0] + bb.x; o.y = acc[i][1] + bb.y;
    o.z = acc[i][2] + bb.z; o.w = acc[i][3] + bb.w;
    *(float4*)(&C[(size_t)row * 64 + tx * 4]) = o;
  }
}

// ---------------- stack init: acc = x = x0 (= [user_src ; item part]) ----------------

__global__ void init_stack(const float4* __restrict__ user_src,
                           const float4* __restrict__ item_src,
                           float4* __restrict__ acc, float4* __restrict__ x,
                           int item_from_acc) {
  int i = blockIdx.x * blockDim.x + threadIdx.x;  // over NNODES*16 float4s
  if (i >= NNODES * 16) return;
  const int UB = NUM_USER * 16;
  float4 v;
  if (i < UB)               { v = user_src[i];      acc[i] = v; }
  else if (item_from_acc)   { v = acc[i]; }            // GEMM already wrote item part
  else                      { v = item_src[i - UB]; acc[i] = v; }
  x[i] = v;
}

// ---------------- aggregation: x = b + D^{-1/2} A D^{-1/2} h ; acc += x ----------------
// one wave per dst node, lane = channel. Unroll-by-2 on edges for MLP.

__global__ __launch_bounds__(256) void aggregate(const float* __restrict__ h,
                                                 const int* __restrict__ indptr,
                                                 const int* __restrict__ col,
                                                 const float* __restrict__ dinv,
                                                 const float* __restrict__ bias,
                                                 float* __restrict__ x,
                                                 float* __restrict__ acc) {
  int n = (int)((blockIdx.x * blockDim.x + threadIdx.x) >> 6);
  int lane = threadIdx.x & 63;
  if (n >= NNODES) return;
  float dn = dinv[n];
  int j0 = indptr[n], j1 = indptr[n + 1];
  float sum0 = dn * h[(size_t)n * 64 + lane];  // self loop (outer dn applied below)
  float sum1 = 0.f;
  int j = j0;
  for (; j + 2 <= j1; j += 2) {
    int s0 = col[j];
    int s1 = col[j + 1];
    float w0 = dinv[s0], w1 = dinv[s1];
    float h0 = h[(size_t)s0 * 64 + lane];
    float h1 = h[(size_t)s1 * 64 + lane];
    sum0 += w0 * h0;
    sum1 += w1 * h1;
  }
  if (j < j1) {
    int s = col[j];
    sum0 += dinv[s] * h[(size_t)s * 64 + lane];
  }
  float val = bias[lane] + dn * (sum0 + sum1);
  size_t o = (size_t)n * 64 + lane;
  x[o] = val;
  acc[o] += val;
}

__global__ void scale_kernel(float4* __restrict__ out) {
  int i = blockIdx.x * blockDim.x + threadIdx.x;
  if (i >= 3 * NNODES * 16) return;
  float4 v = out[i];
  const float s = 1.0f / 3.0f;
  v.x *= s; v.y *= s; v.z *= s; v.w *= s;
  out[i] = v;
}

// ---------------- launch ----------------

extern "C" void kernel_launch(void* const* d_in, const int* in_sizes, int n_in,
                              void* d_out, int out_size, void* d_ws, size_t ws_size,
                              hipStream_t stream) {
  const int*   edge_index = (const int*)d_in[0];
  const float* v_feat     = (const float*)d_in[1];
  const float* t_feat     = (const float*)d_in[2];
  const float* user_emb   = (const float*)d_in[3];
  const float* item_emb   = (const float*)d_in[4];
  const float* user_emb_v = (const float*)d_in[5];
  const float* user_emb_t = (const float*)d_in[6];
  const float* W_v        = (const float*)d_in[7];
  const float* b_v        = (const float*)d_in[8];
  const float* W_t        = (const float*)d_in[9];
  const float* b_t        = (const float*)d_in[10];
  const float* W0         = (const float*)d_in[11];
  const float* b0         = (const float*)d_in[12];
  const float* W1         = (const float*)d_in[13];
  const float* b1         = (const float*)d_in[14];
  float* out = (float*)d_out;

  char* ws = (char*)d_ws;
  size_t off = 0;
  auto alloc = [&](size_t bytes) -> void* {
    void* p = ws + off;
    off = align_up(off + bytes, 256);
    return p;
  };
  int*   cnt    = (int*)alloc((size_t)NNODES * 4);
  int*   cursor = (int*)alloc((size_t)NNODES * 4);
  int*   indptr = (int*)alloc((size_t)(NNODES + 1) * 4);
  int*   psum   = (int*)alloc(128 * 4);
  float* dinv   = (float*)alloc((size_t)NNODES * 4);
  int*   col    = (int*)alloc((size_t)2 * NEDGE * 4);       // 16 MB
  float* h      = (float*)alloc((size_t)NNODES * DIM * 4);  // 25.6 MB
  float* xbuf   = (float*)alloc((size_t)NNODES * DIM * 4);  // 25.6 MB
  (void)ws_size; (void)n_in; (void)in_sizes; (void)out_size;

  // graph build
  hipMemsetAsync(cnt, 0, (size_t)NNODES * 4, stream);
  count_kernel<<<(NEDGE + 255) / 256, 256, 0, stream>>>((const int2*)edge_index, cnt);
  dinv_kernel<<<(NNODES + 255) / 256, 256, 0, stream>>>(cnt, dinv);
  const int NB = (NNODES + 1023) / 1024;  // 98
  scan_part<<<NB, 256, 0, stream>>>(cnt, psum);
  scan_psum_kernel<<<1, 64, 0, stream>>>(psum, NB, indptr);
  scan_final<<<NB, 256, 0, stream>>>(cnt, psum, indptr, cursor);
  fill_kernel<<<(NEDGE + 255) / 256, 256, 0, stream>>>((const int2*)edge_index, cursor, col);

  // feature GEMMs write straight into d_out item regions (they ARE x0's item part)
  float* v_item = out + (size_t)1 * NNODES * DIM + (size_t)NUM_USER * DIM;
  float* t_item = out + (size_t)2 * NNODES * DIM + (size_t)NUM_USER * DIM;
  gemm_nt64<<<(NUM_ITEM + 63) / 64, 256, 0, stream>>>(v_feat, W_v, b_v, v_item, NUM_ITEM, 2048);
  gemm_nt64<<<(NUM_ITEM + 63) / 64, 256, 0, stream>>>(t_feat, W_t, b_t, t_item, NUM_ITEM, 768);

  const float* Ws[2] = {W0, W1};
  const float* bs[2] = {b0, b1};
  const float* usersrc[3] = {user_emb, user_emb_v, user_emb_t};
  for (int s = 0; s < 3; ++s) {
    float* acc = out + (size_t)s * NNODES * DIM;
    init_stack<<<(NNODES * 16 + 255) / 256, 256, 0, stream>>>(
        (const float4*)usersrc[s], (const float4*)item_emb,
        (float4*)acc, (float4*)xbuf, s > 0 ? 1 : 0);
    for (int l = 0; l < 2; ++l) {
      gemm_nt64<<<(NNODES + 63) / 64, 256, 0, stream>>>(xbuf, Ws[l], nullptr, h, NNODES, DIM);
      aggregate<<<(NNODES + 3) / 4, 256, 0, stream>>>(h, indptr, col, dinv, bs[l], xbuf, acc);
    }
  }
  scale_kernel<<<(3 * NNODES * 16 + 255) / 256, 256, 0, stream>>>((float4*)out);
}